// Round 18
// baseline (615.966 us; speedup 1.0000x reference)
//
#include <hip/hip_runtime.h>
#include <hip/hip_bf16.h>
#include <math.h>
#include <stdint.h>

#define BATCH   4
#define SEQ     2048
#define DMODEL  512
#define NHEADS  8
#define HDIM    64
#define QKV_N   (3*DMODEL)   // 1536
#define NBLK    512          // grid size; 2 blocks/CU guaranteed co-resident

typedef short bf8  __attribute__((ext_vector_type(8)));   // 8 bf16 (4 VGPRs)
typedef float f32x4 __attribute__((ext_vector_type(4)));  // 4 fp32 acc

#define MFMA16(a,b,c) __builtin_amdgcn_mfma_f32_16x16x32_bf16((a),(b),(c),0,0,0)

__device__ inline unsigned short f2bf(float f){      // RNE fp32->bf16
  unsigned int u = __float_as_uint(f);
  u += 0x7FFFu + ((u >> 16) & 1u);
  return (unsigned short)(u >> 16);
}

__device__ inline unsigned int pack_bf2(float a, float b){  // v_cvt_pk_bf16_f32
  __hip_bfloat162 h = __float22bfloat162_rn(make_float2(a, b));
  return *reinterpret_cast<unsigned int*>(&h);
}

// raw v_exp_f32: computes 2^x (Q is pre-scaled by 0.125*log2(e) upstream)
__device__ __forceinline__ float exp2_hw(float x){
#if defined(__has_builtin)
#if __has_builtin(__builtin_amdgcn_exp2f)
  return __builtin_amdgcn_exp2f(x);
#else
  float r; asm("v_exp_f32 %0, %1" : "=v"(r) : "v"(x)); return r;
#endif
#else
  float r; asm("v_exp_f32 %0, %1" : "=v"(r) : "v"(x)); return r;
#endif
}

// global -> LDS direct DMA, 16 B per lane (LDS linear; swizzle on global src)
__device__ __forceinline__ void gload_lds16(const unsigned short* g,
                                            unsigned short* l){
  __builtin_amdgcn_global_load_lds(
      (const __attribute__((address_space(1))) unsigned int*)g,
      (__attribute__((address_space(3))) unsigned int*)l,
      16, 0, 0);
}

// Manual grid barrier v2. Round-17 lesson: spinning with atomic RMW
// (atomicAdd(p,0)) serializes ~512 spinners on one cache line at the
// coherent point (~50us/barrier). Fix: spin on a PURE agent-scope atomic
// LOAD (concurrent, no ownership transfer); arrivals = one fetch_add per
// block (512 total); leader publishes generation with release store.
// Agent scope = coherent across XCD L2s (G16). Co-residency guaranteed:
// 512 blocks = 2/CU x 256 CU.
__device__ __forceinline__ void gridbar(unsigned int* bar){
  __syncthreads();
  if (threadIdx.x == 0){
    __threadfence();                                  // release prior writes
    const unsigned int gen =
        __hip_atomic_load(&bar[1], __ATOMIC_RELAXED, __HIP_MEMORY_SCOPE_AGENT);
    const unsigned int arr =
        __hip_atomic_fetch_add(&bar[0], 1u, __ATOMIC_ACQ_REL,
                               __HIP_MEMORY_SCOPE_AGENT);
    if (arr == NBLK - 1u){
      __hip_atomic_store(&bar[0], 0u, __ATOMIC_RELAXED,
                         __HIP_MEMORY_SCOPE_AGENT);
      __hip_atomic_store(&bar[1], gen + 1u, __ATOMIC_RELEASE,
                         __HIP_MEMORY_SCOPE_AGENT);
    } else {
      while (__hip_atomic_load(&bar[1], __ATOMIC_ACQUIRE,
                               __HIP_MEMORY_SCOPE_AGENT) == gen)
        __builtin_amdgcn_s_sleep(8);
    }
    __threadfence();                                  // acquire
  }
  __syncthreads();
}

// ---------------------------------------------------------------------------
// MEGA kernel: all 5 phases in one launch; 4 manual grid barriers replace 4
// kernel launch+drain overheads. Phase bodies identical to the proven
// standalone kernels. Dynamic LDS 36864 B -> 2 blocks/CU (73.7K < 160K).
// ---------------------------------------------------------------------------
__global__ __launch_bounds__(256, 2) void mega(
    const float* __restrict__ x, const int* __restrict__ pmask,
    const float* __restrict__ Wqkv, const float* __restrict__ Wout,
    float* __restrict__ Out, unsigned short* __restrict__ Xh,
    unsigned short* __restrict__ WqkvT, unsigned short* __restrict__ WoutT,
    unsigned short* __restrict__ QKV, unsigned short* __restrict__ VT,
    unsigned short* __restrict__ Ob, int* __restrict__ Idx,
    int* __restrict__ Cnt, unsigned int* __restrict__ bar)
{
  extern __shared__ __align__(16) unsigned char smem[];
  const int bid = blockIdx.x;
  const int t = threadIdx.x;
  const int w = t>>6, lane = t&63, quad = lane>>4, l15 = lane&15;
  const f32x4 Z4 = {0.f,0.f,0.f,0.f};

  //========================= phase 1: prep ==================================
  {
    unsigned short (*Ts)[72] = (unsigned short(*)[72])smem;       // [64][72]
    int* ps  = (int*)(smem + 9216);                               // [256]
    int* tot = (int*)(smem + 9216 + 1024);
    for (int vb = bid; vb < 2820; vb += NBLK) {
      __syncthreads();                         // guard LDS reuse across iters
      if (vb < 2048) {
        const int i = vb*256 + t;
        const float4 a = reinterpret_cast<const float4*>(x)[2*i];
        const float4 b = reinterpret_cast<const float4*>(x)[2*i+1];
        uint4 o; unsigned short* us = reinterpret_cast<unsigned short*>(&o);
        us[0]=f2bf(a.x); us[1]=f2bf(a.y); us[2]=f2bf(a.z); us[3]=f2bf(a.w);
        us[4]=f2bf(b.x); us[5]=f2bf(b.y); us[6]=f2bf(b.z); us[7]=f2bf(b.w);
        reinterpret_cast<uint4*>(Xh)[i] = o;
      } else if (vb >= 2308) {                 // zero Ob (8 MB)
        const int g = (vb - 2308)*256 + t;
        uint4 z = {0u,0u,0u,0u};
        uint4* p = reinterpret_cast<uint4*>(Ob) + (size_t)g*4;
        p[0]=z; p[1]=z; p[2]=z; p[3]=z;
      } else if (vb >= 2304) {                 // mask compaction scan
        const int b = vb - 2304;
        const int* mb = pmask + b*SEQ;
        int loc[8]; int c = 0; const int base = t*8;
#pragma unroll
        for (int j=0;j<8;++j){ const int v = (mb[base+j] != 0); loc[j]=v; c+=v; }
        ps[t] = c; __syncthreads();
        for (int off=1; off<256; off<<=1){     // Hillis-Steele inclusive
          const int v = (t>=off) ? ps[t-off] : 0;
          __syncthreads(); ps[t] += v; __syncthreads();
        }
        int excl = ps[t] - c;
#pragma unroll
        for (int j=0;j<8;++j) if (loc[j]) Idx[b*SEQ + (excl++)] = base + j;
        if (t == 255){ Cnt[b] = ps[255]; *tot = ps[255]; }
        __syncthreads();
        for (int k = *tot + t; k < SEQ; k += 256) Idx[b*SEQ + k] = 0;
      } else {                                 // W transposes
        const float* in; unsigned short* out; int R, C, gx, gy;
        if (vb < 2048 + 192) {
          const int bb = vb - 2048;
          gx = bb % 24; gy = bb / 24; in = Wqkv; out = WqkvT; R = DMODEL; C = QKV_N;
        } else {
          const int bb = vb - 2240;
          gx = bb % 8;  gy = bb / 8;  in = Wout; out = WoutT; R = DMODEL; C = DMODEL;
        }
        const int r0 = gy<<6, c0 = gx<<6;
        const int rr = t>>2, cs = (t&3)<<4;
#pragma unroll
        for (int p=0;p<4;++p){
          float4 v = *reinterpret_cast<const float4*>(in + (size_t)(r0+rr)*C + c0 + cs + p*4);
          Ts[rr][cs+p*4+0]=f2bf(v.x); Ts[rr][cs+p*4+1]=f2bf(v.y);
          Ts[rr][cs+p*4+2]=f2bf(v.z); Ts[rr][cs+p*4+3]=f2bf(v.w);
        }
        __syncthreads();
        const int cc = t>>2, rs = (t&3)<<4;
#pragma unroll
        for (int p=0;p<4;++p){
          ushort4 o;
          o.x = Ts[rs+p*4+0][cc]; o.y = Ts[rs+p*4+1][cc];
          o.z = Ts[rs+p*4+2][cc]; o.w = Ts[rs+p*4+3][cc];
          *reinterpret_cast<ushort4*>(out + (size_t)(c0+cc)*R + r0 + rs + p*4) = o;
        }
      }
    }
  }
  gridbar(bar);

  //==================== phase 2: gemm_qkv (768 virtual) =====================
  {
    unsigned short (*As)[64] = (unsigned short(*)[64])smem;          // [128][64]
    unsigned short (*Bs)[64] = (unsigned short(*)[64])(smem + 16384);// [128][64]
    const int wr = (w>>1)<<6, wc = (w&1)<<6;
    const int row = t>>3, seg = t&7;
    const int sa = (seg ^ (row & 7)) << 3;             // A source chunk-swizzle
    const int sb = (seg ^ ((row >> 2) & 7)) << 3;      // B source chunk-swizzle
    for (int vb = bid; vb < 768; vb += NBLK) {
      const int swz = (vb & 7)*96 + (vb >> 3);         // bijective (768%8==0)
      const int m0 = (swz/12)<<7, n0 = (swz%12)<<7;
      const unsigned short* Agp = Xh    + (size_t)(m0+row)*DMODEL + sa;
      const unsigned short* Bgp = WqkvT + (size_t)(n0+row)*DMODEL + sb;
      f32x4 acc[4][4];
#pragma unroll
      for (int i=0;i<4;++i)
#pragma unroll
        for (int j=0;j<4;++j) acc[i][j] = Z4;
      for (int k0=0;k0<DMODEL;k0+=64){
        __syncthreads();
#pragma unroll
        for (int p=0;p<4;++p){
          gload_lds16(Agp + (size_t)p*32*DMODEL + k0, &As[(w<<3)+(p<<5)][0]);
          gload_lds16(Bgp + (size_t)p*32*DMODEL + k0, &Bs[(w<<3)+(p<<5)][0]);
        }
        __syncthreads();
#pragma unroll
        for (int ks=0;ks<2;++ks){
          const int co = (((ks<<2)|quad) ^ (l15&7)) << 3;
          bf8 af[4], bfr[4];
#pragma unroll
          for (int mi=0;mi<4;++mi)
            af[mi]  = *reinterpret_cast<const bf8*>(&As[wr+mi*16+l15][co]);
#pragma unroll
          for (int nj=0;nj<4;++nj)
            bfr[nj] = *reinterpret_cast<const bf8*>(&Bs[wc+(l15<<2)+nj][co]);
#pragma unroll
          for (int mi=0;mi<4;++mi)
#pragma unroll
            for (int nj=0;nj<4;++nj) acc[mi][nj] = MFMA16(af[mi], bfr[nj], acc[mi][nj]);
        }
      }
      const int cbase = n0 + wc + (l15<<2);
      bool isq[4];
#pragma unroll
      for (int nj=0;nj<4;++nj) isq[nj] = ((cbase+nj) % 192) < 64;
#pragma unroll
      for (int mi=0;mi<4;++mi)
#pragma unroll
        for (int i=0;i<4;++i){
          const int m = m0 + wr + mi*16 + quad*4 + i;
          unsigned long long pk = 0;
#pragma unroll
          for (int nj=0;nj<4;++nj){
            float v = acc[mi][nj][i];
            if (isq[nj]) v *= 0.18033688f;             // 0.125 * log2(e)
            pk |= (unsigned long long)f2bf(v) << (16*nj);
          }
          *reinterpret_cast<unsigned long long*>(QKV + (size_t)m*QKV_N + cbase) = pk;
        }
      __syncthreads();                                 // LDS reads done before next vb
    }
  }
  gridbar(bar);

  //=================== phase 3: v_transpose (1024 virtual) ==================
  {
    unsigned short (*Td)[76] = (unsigned short(*)[76])smem;          // [64][76]
    for (int vb = bid; vb < 1024; vb += NBLK) {
      __syncthreads();                                 // LDS reuse guard
      const int bh = vb >> 5, b = bh>>3, hp = bh&7;
      const int s0 = (vb & 31) << 6;
      if (s0 >= ((Cnt[b] + 63) & ~63)) continue;       // dead tile
      const size_t rbase = (size_t)(b*SEQ + hp*256);
      const int sr = t>>2, db = (t&3)<<4;
      const int s = Idx[b*SEQ + s0 + sr];
      const unsigned short* vp =
          QKV + (rbase + (s>>3))*QKV_N + (s&7)*192 + 128 + db;
      uint4 a = *reinterpret_cast<const uint4*>(vp);
      uint4 c = *reinterpret_cast<const uint4*>(vp + 8);
      const unsigned short* ua = reinterpret_cast<const unsigned short*>(&a);
      const unsigned short* uc = reinterpret_cast<const unsigned short*>(&c);
#pragma unroll
      for (int j=0;j<8;++j) Td[db+j][sr]   = ua[j];
#pragma unroll
      for (int j=0;j<8;++j) Td[db+8+j][sr] = uc[j];
      __syncthreads();
      const int L = t&15, d0 = t>>4;
      unsigned short* Op = VT + (size_t)bh*HDIM*SEQ + s0 + (L<<2);
#pragma unroll
      for (int cc=0;cc<4;++cc){
        const int d = d0 + (cc<<4);
        *reinterpret_cast<unsigned long long*>(Op + (size_t)d*SEQ) =
            *reinterpret_cast<const unsigned long long*>(&Td[d][L<<2]);
      }
    }
  }
  gridbar(bar);

  //========================= phase 4: attn (512) ============================
  {
    unsigned short (*Ks)[72] = (unsigned short(*)[72])smem;           // [64][72]
    unsigned short (*Vs)[72] = (unsigned short(*)[72])(smem + 9216);  // [64][72]
    unsigned short (*Pl)[32][72] = (unsigned short(*)[32][72])(smem + 18432);
    const int swz = (bid & 7)*64 + (bid >> 3);          // bijective
    const int bh = swz >> 4, b = bh>>3, hp = bh&7;
    const int q0 = (swz & 15) << 7;                     // 128 q/block
    const int kcnt = Cnt[b];
    const int kend = (kcnt + 63) & ~63;
    if (q0 < kend) {
      const int* Idxb = Idx + b*SEQ;
      const int qs = q0 + (w<<5);                       // 32 q/wave
      const size_t rbase = (size_t)(b*SEQ + hp*256);
      bf8 qf[2][2];
#pragma unroll
      for (int a=0;a<2;++a){
        const int sq = Idxb[qs + a*16 + l15];           // virtual gather
        const unsigned short* qp =
            QKV + (rbase + (sq>>3))*QKV_N + (sq&7)*192 + (quad<<3);
        qf[a][0] = *reinterpret_cast<const bf8*>(qp);
        qf[a][1] = *reinterpret_cast<const bf8*>(qp + 32);
      }
      const unsigned short* Vg = VT + (size_t)bh*HDIM*SEQ;
      bf8 ones;
#pragma unroll
      for (int j=0;j<8;++j) ones[j] = (short)0x3F80;    // bf16 1.0
      const int srow = t>>2, sc4 = (t&3)<<4;
      const int krow = ((srow&3)<<4) + (srow>>2);       // rho(srow)
      f32x4 of[2][4]; f32x4 lsv[2];
#pragma unroll
      for (int a=0;a<2;++a){ lsv[a]=Z4;
#pragma unroll
        for (int i=0;i<4;++i) of[a][i]=Z4; }
      uint4 gk0, gk1, gv0, gv1;
      {                                                 // prefetch tile 0
        const int s = Idxb[srow];
        const unsigned short* kp =
            QKV + (rbase + (s>>3))*QKV_N + (s&7)*192 + 64 + sc4;
        gk0 = *reinterpret_cast<const uint4*>(kp);
        gk1 = *reinterpret_cast<const uint4*>(kp + 8);
        const unsigned short* vp = Vg + (size_t)srow*SEQ + sc4;
        gv0 = *reinterpret_cast<const uint4*>(vp);
        gv1 = *reinterpret_cast<const uint4*>(vp + 8);
      }
      for (int kt=0; kt<kend; kt+=64){
        *reinterpret_cast<uint4*>(&Ks[krow][sc4])   = gk0;
        *reinterpret_cast<uint4*>(&Ks[krow][sc4+8]) = gk1;
        *reinterpret_cast<uint4*>(&Vs[srow][sc4])   = gv0;
        *reinterpret_cast<uint4*>(&Vs[srow][sc4+8]) = gv1;
        __syncthreads();                                // tiles visible
        if (kt + 64 < kend){                            // prefetch next
          const int s = Idxb[kt + 64 + srow];
          const unsigned short* kp =
              QKV + (rbase + (s>>3))*QKV_N + (s&7)*192 + 64 + sc4;
          gk0 = *reinterpret_cast<const uint4*>(kp);
          gk1 = *reinterpret_cast<const uint4*>(kp + 8);
          const unsigned short* vp = Vg + (size_t)srow*SEQ + (kt + 64) + sc4;
          gv0 = *reinterpret_cast<const uint4*>(vp);
          gv1 = *reinterpret_cast<const uint4*>(vp + 8);
        }
        bf8 kf[4][2];
#pragma unroll
        for (int nf=0;nf<4;++nf){
          kf[nf][0] = *reinterpret_cast<const bf8*>(&Ks[nf*16+l15][quad<<3]);
          kf[nf][1] = *reinterpret_cast<const bf8*>(&Ks[nf*16+l15][32+(quad<<3)]);
        }
#pragma unroll
        for (int a=0;a<2;++a){
          f32x4 sc[4];
          __builtin_amdgcn_s_setprio(1);
#pragma unroll
          for (int nf=0;nf<4;++nf){
            f32x4 s = MFMA16(qf[a][0], kf[nf][0], Z4);
            sc[nf] = MFMA16(qf[a][1], kf[nf][1], s);
          }
          __builtin_amdgcn_s_setprio(0);
          float pv[4][4];
#pragma unroll
          for (int nf=0;nf<4;++nf){
            const bool on = (kt + (l15<<2) + nf) < kcnt;  // tail mask only
#pragma unroll
            for (int i=0;i<4;++i)
              pv[nf][i] = on ? exp2_hw(sc[nf][i]) : 0.f;
          }
#pragma unroll
          for (int i=0;i<4;++i){
            const unsigned int lo = pack_bf2(pv[0][i], pv[1][i]);
            const unsigned int hi = pack_bf2(pv[2][i], pv[3][i]);
            *reinterpret_cast<unsigned long long*>(&Pl[w][a*16+(quad<<2)+i][l15<<2]) =
                ((unsigned long long)hi<<32) | lo;
          }
        }
        bf8 pa[2][2];
#pragma unroll
        for (int a=0;a<2;++a){
          pa[a][0] = *reinterpret_cast<const bf8*>(&Pl[w][a*16+l15][quad<<3]);
          pa[a][1] = *reinterpret_cast<const bf8*>(&Pl[w][a*16+l15][32+(quad<<3)]);
        }
        __builtin_amdgcn_s_setprio(1);
#pragma unroll
        for (int a=0;a<2;++a){                          // lsum on MFMA pipe
          f32x4 l = MFMA16(pa[a][0], ones, lsv[a]);
          lsv[a] = MFMA16(pa[a][1], ones, l);
        }
#pragma unroll
        for (int nf=0;nf<4;++nf){
          const bf8 v0 = *reinterpret_cast<const bf8*>(&Vs[nf*16+l15][quad<<3]);
          const bf8 v1 = *reinterpret_cast<const bf8*>(&Vs[nf*16+l15][32+(quad<<3)]);
#pragma unroll
          for (int a=0;a<2;++a){
            f32x4 o = MFMA16(pa[a][0], v0, of[a][nf]);
            of[a][nf] = MFMA16(pa[a][1], v1, o);
          }
        }
        __builtin_amdgcn_s_setprio(0);
        __syncthreads();                                // reads done, bufs free
      }
      unsigned short* Op = Ob + (size_t)bh*SEQ*HDIM;
#pragma unroll
      for (int a=0;a<2;++a)
#pragma unroll
        for (int i=0;i<4;++i){
          const int qc = qs + a*16 + (quad<<2) + i;     // compacted q index
          if (qc < kcnt){
            const int orig = Idxb[qc];
            const float l = lsv[a][i];
            const float inv = (l > 0.f) ? 1.f/l : 0.f;
#pragma unroll
            for (int nf=0;nf<4;++nf)
              Op[(size_t)orig*HDIM + (nf<<4) + l15] = f2bf(of[a][nf][i]*inv);
          }
        }
    }
  }
  gridbar(bar);

  //======================== phase 5: gemm_out (512) =========================
  {
    unsigned short (*As)[64] = (unsigned short(*)[64])smem;          // [128][64]
    unsigned short (*Bs)[64] = (unsigned short(*)[64])(smem + 16384);// [64][64]
    const int wr = (w>>1)<<6, wc = (w&1)<<5;
    const int swz = (bid & 7)*64 + (bid >> 3);          // bijective
    const int m0 = (swz>>3)<<7, n0 = (swz&7)<<6;
    const int row = t>>3, seg = t&7;
    const int sa = (seg ^ (row & 7)) << 3;
    const int sb = (seg ^ ((row >> 1) & 7)) << 3;
    const unsigned short* Agp = Ob    + (size_t)(m0+row)*DMODEL + sa;
    const unsigned short* Bgp = WoutT + (size_t)(n0+row)*DMODEL + sb;
    f32x4 acc[4][2];
#pragma unroll
    for (int i=0;i<4;++i)
#pragma unroll
      for (int j=0;j<2;++j) acc[i][j] = Z4;
    for (int k0=0;k0<DMODEL;k0+=64){
      __syncthreads();
#pragma unroll
      for (int p=0;p<4;++p)
        gload_lds16(Agp + (size_t)p*32*DMODEL + k0, &As[(w<<3)+(p<<5)][0]);
#pragma unroll
      for (int p=0;p<2;++p)
        gload_lds16(Bgp + (size_t)p*32*DMODEL + k0, &Bs[(w<<3)+(p<<5)][0]);
      __syncthreads();
#pragma unroll
      for (int ks=0;ks<2;++ks){
        const int co = (((ks<<2)|quad) ^ (l15&7)) << 3;
        bf8 af[4], bfr[2];
#pragma unroll
        for (int mi=0;mi<4;++mi)
          af[mi]  = *reinterpret_cast<const bf8*>(&As[wr+mi*16+l15][co]);
#pragma unroll
        for (int nj=0;nj<2;++nj)
          bfr[nj] = *reinterpret_cast<const bf8*>(&Bs[wc+(l15<<1)+nj][co]);
#pragma unroll
        for (int mi=0;mi<4;++mi)
#pragma unroll
          for (int nj=0;nj<2;++nj) acc[mi][nj] = MFMA16(af[mi], bfr[nj], acc[mi][nj]);
      }
    }
    const int cbase = n0 + wc + (l15<<1);
#pragma unroll
    for (int mi=0;mi<4;++mi)
#pragma unroll
      for (int i=0;i<4;++i){
        const int m = m0 + wr + mi*16 + quad*4 + i;
        const float2 o = make_float2(acc[mi][0][i], acc[mi][1][i]);
        *reinterpret_cast<float2*>(Out + (size_t)m*DMODEL + cbase) = o;
      }
  }
}

// ---------------------------------------------------------------------------
extern "C" void kernel_launch(void* const* d_in, const int* in_sizes, int n_in,
                              void* d_out, int out_size, void* d_ws, size_t ws_size,
                              hipStream_t stream) {
  (void)in_sizes; (void)n_in; (void)out_size; (void)ws_size;
  const float* x     = (const float*)d_in[0];
  const int*   pmask = (const int*)d_in[2];
  const float* Wqkv  = (const float*)d_in[3];
  const float* Wout  = (const float*)d_in[4];
  float* out = (float*)d_out;

  const size_t per = (size_t)BATCH*NHEADS*SEQ*HDIM;     // 4,194,304
  unsigned short* Xh    = (unsigned short*)d_ws;
  unsigned short* WqkvT = Xh    + (size_t)8192*512;
  unsigned short* WoutT = WqkvT + (size_t)1536*512;
  unsigned short* QKVb  = WoutT + (size_t)512*512;
  unsigned short* VbT   = QKVb  + (size_t)8192*QKV_N;
  unsigned short* Ob    = VbT + per;
  int* Idx = (int*)(Ob + per);                          // [BATCH][SEQ]
  int* Cnt = Idx + (size_t)BATCH*SEQ;                   // [BATCH]
  unsigned int* bar = (unsigned int*)(Cnt + BATCH);     // [2] barrier state

  hipMemsetAsync(bar, 0, 16, stream);                   // zero barrier state
  mega<<<dim3(NBLK), dim3(256), 36864, stream>>>(
      x, pmask, Wqkv, Wout, out, Xh, WqkvT, WoutT, QKVb, VbT, Ob,
      Idx, Cnt, bar);
}

// Round 19
// 153.864 us; speedup vs baseline: 4.0033x; 4.0033x over previous
//
#include <hip/hip_runtime.h>
#include <hip/hip_bf16.h>
#include <math.h>
#include <stdint.h>

#define BATCH   4
#define SEQ     2048
#define DMODEL  512
#define NHEADS  8
#define HDIM    64
#define QKV_N   (3*DMODEL)   // 1536

typedef short bf8  __attribute__((ext_vector_type(8)));   // 8 bf16 (4 VGPRs)
typedef float f32x4 __attribute__((ext_vector_type(4)));  // 4 fp32 acc

#define MFMA16(a,b,c) __builtin_amdgcn_mfma_f32_16x16x32_bf16((a),(b),(c),0,0,0)

__device__ inline unsigned short f2bf(float f){      // RNE fp32->bf16
  unsigned int u = __float_as_uint(f);
  u += 0x7FFFu + ((u >> 16) & 1u);
  return (unsigned short)(u >> 16);
}

__device__ inline unsigned int pack_bf2(float a, float b){  // v_cvt_pk_bf16_f32
  __hip_bfloat162 h = __float22bfloat162_rn(make_float2(a, b));
  return *reinterpret_cast<unsigned int*>(&h);
}

// raw v_exp_f32: computes 2^x (Q is pre-scaled by 0.125*log2(e) upstream)
__device__ __forceinline__ float exp2_hw(float x){
#if defined(__has_builtin)
#if __has_builtin(__builtin_amdgcn_exp2f)
  return __builtin_amdgcn_exp2f(x);
#else
  float r; asm("v_exp_f32 %0, %1" : "=v"(r) : "v"(x)); return r;
#endif
#else
  float r; asm("v_exp_f32 %0, %1" : "=v"(r) : "v"(x)); return r;
#endif
}

// global -> LDS direct DMA, 16 B per lane. LDS dest = wave-uniform base +
// lane*16 (LDS stays LINEAR; swizzles are applied on the per-lane GLOBAL
// source address + matching read offset — rule #21 both-sides involution).
__device__ __forceinline__ void gload_lds16(const unsigned short* g,
                                            unsigned short* l){
  __builtin_amdgcn_global_load_lds(
      (const __attribute__((address_space(1))) unsigned int*)g,
      (__attribute__((address_space(3))) unsigned int*)l,
      16, 0, 0);
}

// ---------------------------------------------------------------------------
// Fused prepass: cast x -> bf16 (0..2047), transpose+cast W_qkv (2048..2239),
// transpose+cast W_out (2240..2303), per-batch valid-position compaction scan
// in VIRTUAL space (2304..2307), zero Ob (2308..2819).
// ---------------------------------------------------------------------------
__global__ __launch_bounds__(256) void prep(
    const float* __restrict__ x, const float* __restrict__ Wqkv,
    const float* __restrict__ Wout, const int* __restrict__ pmask,
    unsigned short* __restrict__ Xh, unsigned short* __restrict__ WqkvT,
    unsigned short* __restrict__ WoutT, int* __restrict__ Idx,
    int* __restrict__ Cnt, unsigned short* __restrict__ Ob)
{
  __shared__ unsigned short Ts[64][72];
  __shared__ int ps[256];
  __shared__ int tot;
  const int t = threadIdx.x;
  const int bx = blockIdx.x;
  if (bx < 2048) {
    const int i = bx*256 + t;
    const float4 a = reinterpret_cast<const float4*>(x)[2*i];
    const float4 b = reinterpret_cast<const float4*>(x)[2*i+1];
    uint4 o; unsigned short* us = reinterpret_cast<unsigned short*>(&o);
    us[0]=f2bf(a.x); us[1]=f2bf(a.y); us[2]=f2bf(a.z); us[3]=f2bf(a.w);
    us[4]=f2bf(b.x); us[5]=f2bf(b.y); us[6]=f2bf(b.z); us[7]=f2bf(b.w);
    reinterpret_cast<uint4*>(Xh)[i] = o;
    return;
  }
  if (bx >= 2308) {                                  // zero Ob (8 MB)
    const int g = (bx - 2308)*256 + t;
    uint4 z = {0u,0u,0u,0u};
    uint4* p = reinterpret_cast<uint4*>(Ob) + (size_t)g*4;
    p[0]=z; p[1]=z; p[2]=z; p[3]=z;
    return;
  }
  if (bx >= 2304) {                                  // mask compaction scan
    const int b = bx - 2304;
    const int* mb = pmask + b*SEQ;
    int loc[8]; int c = 0; const int base = t*8;
#pragma unroll
    for (int j=0;j<8;++j){ const int v = (mb[base+j] != 0); loc[j]=v; c+=v; }
    ps[t] = c; __syncthreads();
    for (int off=1; off<256; off<<=1){               // Hillis-Steele inclusive
      const int v = (t>=off) ? ps[t-off] : 0;
      __syncthreads(); ps[t] += v; __syncthreads();
    }
    int excl = ps[t] - c;
#pragma unroll
    for (int j=0;j<8;++j) if (loc[j]) Idx[b*SEQ + (excl++)] = base + j;
    if (t == 255){ Cnt[b] = ps[255]; tot = ps[255]; }
    __syncthreads();
    for (int k = tot + t; k < SEQ; k += 256) Idx[b*SEQ + k] = 0;
    return;
  }
  const float* in; unsigned short* out; int R, C, gx, gy;
  if (bx < 2048 + 192) {
    const int bid = bx - 2048;
    gx = bid % 24; gy = bid / 24; in = Wqkv; out = WqkvT; R = DMODEL; C = QKV_N;
  } else {
    const int bid = bx - 2240;
    gx = bid % 8;  gy = bid / 8;  in = Wout; out = WoutT; R = DMODEL; C = DMODEL;
  }
  const int r0 = gy<<6, c0 = gx<<6;
  const int rr = t>>2, cs = (t&3)<<4;
#pragma unroll
  for (int p=0;p<4;++p){
    float4 v = *reinterpret_cast<const float4*>(in + (size_t)(r0+rr)*C + c0 + cs + p*4);
    Ts[rr][cs+p*4+0]=f2bf(v.x); Ts[rr][cs+p*4+1]=f2bf(v.y);
    Ts[rr][cs+p*4+2]=f2bf(v.z); Ts[rr][cs+p*4+3]=f2bf(v.w);
  }
  __syncthreads();
  const int cc = t>>2, rs = (t&3)<<4;
#pragma unroll
  for (int p=0;p<4;++p){
    ushort4 o;
    o.x = Ts[rs+p*4+0][cc]; o.y = Ts[rs+p*4+1][cc];
    o.z = Ts[rs+p*4+2][cc]; o.w = Ts[rs+p*4+3][cc];
    *reinterpret_cast<ushort4*>(out + (size_t)(c0+cc)*R + r0 + rs + p*4) = o;
  }
}

// ---------------------------------------------------------------------------
// MFMA GEMM A v3: chunk-swizzled + LDS-double-buffered gload_lds pipeline.
// Per K-step: issue loads(k+1)->buf[cur^1] FIRST, compute buf[cur], ONE
// barrier (drains vmcnt -> k+1 landed; cur reads done). Zero VGPR cost.
// ---------------------------------------------------------------------------
__global__ __launch_bounds__(256) void gemm_qkv_mfma(
    const unsigned short* __restrict__ A, const unsigned short* __restrict__ Bt,
    unsigned short* __restrict__ QKV)
{
  __shared__ unsigned short As[2][128][64];
  __shared__ unsigned short Bs[2][128][64];
  const int t = threadIdx.x;
  const int w = t>>6, lane = t&63, quad = lane>>4, l15 = lane&15;
  const int wr = (w>>1)<<6, wc = (w&1)<<6;
  const int linear = blockIdx.y*12 + blockIdx.x;     // 768 blocks
  const int swz = (linear & 7)*96 + (linear >> 3);   // bijective (768%8==0)
  const int m0 = (swz/12)<<7, n0 = (swz%12)<<7;
  const int row = t>>3, seg = t&7;
  const int sa = (seg ^ (row & 7)) << 3;             // A source chunk-swizzle
  const int sb = (seg ^ ((row >> 2) & 7)) << 3;      // B source chunk-swizzle
  const unsigned short* Agp = A  + (size_t)(m0+row)*DMODEL + sa;
  const unsigned short* Bgp = Bt + (size_t)(n0+row)*DMODEL + sb;
  f32x4 acc[4][4];
#pragma unroll
  for (int i=0;i<4;++i)
#pragma unroll
    for (int j=0;j<4;++j) acc[i][j] = (f32x4){0.f,0.f,0.f,0.f};

  // prologue: stage k0=0 into buf 0
#pragma unroll
  for (int p=0;p<4;++p){
    gload_lds16(Agp + (size_t)p*32*DMODEL, &As[0][(w<<3)+(p<<5)][0]);
    gload_lds16(Bgp + (size_t)p*32*DMODEL, &Bs[0][(w<<3)+(p<<5)][0]);
  }
  __syncthreads();                                   // buf0 ready

#pragma unroll
  for (int kk=0; kk<DMODEL/64; ++kk){
    const int cur = kk & 1;
    if (kk + 1 < DMODEL/64){                         // loads for k+1 in flight
#pragma unroll
      for (int p=0;p<4;++p){
        gload_lds16(Agp + (size_t)p*32*DMODEL + (kk+1)*64,
                    &As[cur^1][(w<<3)+(p<<5)][0]);
        gload_lds16(Bgp + (size_t)p*32*DMODEL + (kk+1)*64,
                    &Bs[cur^1][(w<<3)+(p<<5)][0]);
      }
    }
#pragma unroll
    for (int ks=0;ks<2;++ks){
      const int co = (((ks<<2)|quad) ^ (l15&7)) << 3;  // swizzled read offset
      bf8 af[4], bfr[4];
#pragma unroll
      for (int mi=0;mi<4;++mi)
        af[mi]  = *reinterpret_cast<const bf8*>(&As[cur][wr+mi*16+l15][co]);
#pragma unroll
      for (int nj=0;nj<4;++nj)
        bfr[nj] = *reinterpret_cast<const bf8*>(&Bs[cur][wc+(l15<<2)+nj][co]);
#pragma unroll
      for (int mi=0;mi<4;++mi)
#pragma unroll
        for (int nj=0;nj<4;++nj) acc[mi][nj] = MFMA16(af[mi], bfr[nj], acc[mi][nj]);
    }
    __syncthreads();                                 // k+1 landed; cur reads done
  }
  const int cbase = n0 + wc + (l15<<2);
  bool isq[4];
#pragma unroll
  for (int nj=0;nj<4;++nj) isq[nj] = ((cbase+nj) % 192) < 64;
#pragma unroll
  for (int mi=0;mi<4;++mi)
#pragma unroll
    for (int i=0;i<4;++i){
      const int m = m0 + wr + mi*16 + quad*4 + i;
      unsigned long long pk = 0;
#pragma unroll
      for (int nj=0;nj<4;++nj){
        float v = acc[mi][nj][i];
        if (isq[nj]) v *= 0.18033688f;               // 0.125 * log2(e)
        pk |= (unsigned long long)f2bf(v) << (16*nj);
      }
      *reinterpret_cast<unsigned long long*>(QKV + (size_t)m*QKV_N + cbase) = pk;
    }
}

// ---------------------------------------------------------------------------
// V^T builder (compacted in VIRTUAL space): VT[bh][d][j] = V of virtual
// position Idx[b][j]. Tiles beyond ceil64(cnt[b]) exit (never read).
// ---------------------------------------------------------------------------
__global__ __launch_bounds__(256) void v_transpose(
    const unsigned short* __restrict__ QKV, const int* __restrict__ Idx,
    const int* __restrict__ Cnt, unsigned short* __restrict__ VT)
{
  __shared__ unsigned short Td[64][76];
  const int t = threadIdx.x;
  const int bh = blockIdx.y, b = bh>>3, hp = bh&7;
  const int s0 = blockIdx.x<<6;
  if (s0 >= ((Cnt[b] + 63) & ~63)) return;           // dead tile
  const size_t rbase = (size_t)(b*SEQ + hp*256);
  const int sr = t>>2, db = (t&3)<<4;
  const int s = Idx[b*SEQ + s0 + sr];                // gather source key
  const unsigned short* vp =
      QKV + (rbase + (s>>3))*QKV_N + (s&7)*192 + 128 + db;
  uint4 a = *reinterpret_cast<const uint4*>(vp);
  uint4 c = *reinterpret_cast<const uint4*>(vp + 8);
  const unsigned short* ua = reinterpret_cast<const unsigned short*>(&a);
  const unsigned short* uc = reinterpret_cast<const unsigned short*>(&c);
#pragma unroll
  for (int j=0;j<8;++j) Td[db+j][sr]   = ua[j];
#pragma unroll
  for (int j=0;j<8;++j) Td[db+8+j][sr] = uc[j];
  __syncthreads();
  const int L = t&15, d0 = t>>4;
  unsigned short* Op = VT + (size_t)bh*HDIM*SEQ + s0 + (L<<2);
#pragma unroll
  for (int cc=0;cc<4;++cc){
    const int d = d0 + (cc<<4);
    *reinterpret_cast<unsigned long long*>(Op + (size_t)d*SEQ) =
        *reinterpret_cast<const unsigned long long*>(&Td[d][L<<2]);
  }
}

// ---------------------------------------------------------------------------
// MFMA flash attention v14: q-compaction on the 8-wave 128q/block geometry.
// Q/K gathered via Idx; VT pre-compacted; tail key mask (pos < cnt);
// epilogue scatters to ORIGINAL positions (Ob pre-zeroed).
// ---------------------------------------------------------------------------
__global__ __launch_bounds__(512, 4) void attn_mfma(
    const unsigned short* __restrict__ QKV, const unsigned short* __restrict__ VT,
    const int* __restrict__ Idx, const int* __restrict__ Cnt,
    unsigned short* __restrict__ O)
{
  __shared__ unsigned short Ks[2][64][72];   // rho-permuted K tiles [row][d]
  __shared__ unsigned short Vs[2][64][72];   // V^T tiles [d][key]
  __shared__ unsigned short Pl[8][16][72];   // wave-private P [q][key]
  const int t = threadIdx.x;
  const int w = t>>6, lane = t&63, quad = lane>>4, l15 = lane&15;
  const int linear = blockIdx.y*16 + blockIdx.x;     // 512 blocks
  const int swz = (linear & 7)*64 + (linear >> 3);   // bijective (512%8==0)
  const int bh = swz >> 4, b = bh>>3, hp = bh&7;
  const int q0 = (swz & 15) << 7;            // 128 queries per block
  const int kcnt = Cnt[b];
  const int kend = (kcnt + 63) & ~63;                // compacted tile span
  if (q0 >= kend) return;                            // dead q-tile (block-uniform)
  const int qs = q0 + (w<<4);                // 16 per wave
  const int* Idxb = Idx + b*SEQ;
  const f32x4 Z4 = {0.f,0.f,0.f,0.f};

  const size_t rbase = (size_t)(b*SEQ + hp*256);   // qkv row base for this bh
  bf8 qf[2];
  {
    const int sq = Idxb[qs + l15];                   // virtual-space gather
    const unsigned short* qp =
        QKV + (rbase + (sq>>3))*QKV_N + (sq&7)*192 + (quad<<3);
    qf[0] = *reinterpret_cast<const bf8*>(qp);
    qf[1] = *reinterpret_cast<const bf8*>(qp + 32);
  }
  const unsigned short* Vg = VT + (size_t)bh*HDIM*SEQ;

  bf8 ones;
#pragma unroll
  for (int j=0;j<8;++j) ones[j] = (short)0x3F80;    // bf16 1.0

  const int srow = t>>3, sc8 = (t&7)<<3;             // staging: key row, col
  const int krow = ((srow&3)<<4) + (srow>>2);        // rho(srow)

  f32x4 of[4]; f32x4 lsv = Z4;
#pragma unroll
  for (int i=0;i<4;++i) of[i]=Z4;

  uint4 gk0, gv0;
  {                                                  // load tile 0 (gathered)
    const int s = Idxb[srow];
    const unsigned short* kp =
        QKV + (rbase + (s>>3))*QKV_N + (s&7)*192 + 64 + sc8;
    gk0 = *reinterpret_cast<const uint4*>(kp);
    gv0 = *reinterpret_cast<const uint4*>(Vg + (size_t)srow*SEQ + sc8);
  }
  // write buf0 (waits on tile-0 loads), then issue tile-1 loads
  *reinterpret_cast<uint4*>(&Ks[0][krow][sc8]) = gk0;
  *reinterpret_cast<uint4*>(&Vs[0][srow][sc8]) = gv0;
  {
    const int s = Idxb[64 + srow];
    const unsigned short* kp =
        QKV + (rbase + (s>>3))*QKV_N + (s&7)*192 + 64 + sc8;
    gk0 = *reinterpret_cast<const uint4*>(kp);
    gv0 = *reinterpret_cast<const uint4*>(Vg + (size_t)srow*SEQ + 64 + sc8);
  }
  __syncthreads();                                   // buf0 visible

  auto iter = [&](unsigned short (&KSC)[64][72], unsigned short (&VSC)[64][72],
                  unsigned short (&KSN)[64][72], unsigned short (&VSN)[64][72],
                  int kt) {
    if (kt + 64 < kend){                             // stage tile t+1 -> NXT
      *reinterpret_cast<uint4*>(&KSN[krow][sc8]) = gk0;
      *reinterpret_cast<uint4*>(&VSN[srow][sc8]) = gv0;
    }
    if (kt + 128 < kend){                            // issue loads tile t+2
      const int s = Idxb[kt + 128 + srow];
      const unsigned short* kp =
          QKV + (rbase + (s>>3))*QKV_N + (s&7)*192 + 64 + sc8;
      gk0 = *reinterpret_cast<const uint4*>(kp);
      gv0 = *reinterpret_cast<const uint4*>(
          Vg + (size_t)srow*SEQ + (kt + 128) + sc8);
    }

    bf8 kf[4][2];
#pragma unroll
    for (int nf=0;nf<4;++nf){
      kf[nf][0] = *reinterpret_cast<const bf8*>(&KSC[nf*16+l15][quad<<3]);
      kf[nf][1] = *reinterpret_cast<const bf8*>(&KSC[nf*16+l15][32+(quad<<3)]);
    }

    f32x4 sc[4];
    __builtin_amdgcn_s_setprio(1);
#pragma unroll
    for (int nf=0;nf<4;++nf){
      f32x4 s = MFMA16(qf[0], kf[nf][0], Z4);
      sc[nf] = MFMA16(qf[1], kf[nf][1], s);
    }
    __builtin_amdgcn_s_setprio(0);
    const int kbase = kt + (l15<<2);
    float pv[4][4];
#pragma unroll
    for (int nf=0;nf<4;++nf){
      const bool on = (kbase + nf) < kcnt;           // tail-tile mask only
#pragma unroll
      for (int i=0;i<4;++i)
        pv[nf][i] = on ? exp2_hw(sc[nf][i]) : 0.f;   // Q pre-scaled 0.125*log2e
    }
#pragma unroll
    for (int i=0;i<4;++i){
      const unsigned int lo = pack_bf2(pv[0][i], pv[1][i]);
      const unsigned int hi = pack_bf2(pv[2][i], pv[3][i]);
      *reinterpret_cast<unsigned long long*>(&Pl[w][(quad<<2)+i][l15<<2]) =
          ((unsigned long long)hi<<32) | lo;
    }

    bf8 pa[2];
    pa[0] = *reinterpret_cast<const bf8*>(&Pl[w][l15][quad<<3]);
    pa[1] = *reinterpret_cast<const bf8*>(&Pl[w][l15][32+(quad<<3)]);
    __builtin_amdgcn_s_setprio(1);
    {                                                // lsum on the MFMA pipe
      f32x4 l = MFMA16(pa[0], ones, lsv);
      lsv = MFMA16(pa[1], ones, l);
    }
#pragma unroll
    for (int nf=0;nf<4;++nf){
      const bf8 v0 = *reinterpret_cast<const bf8*>(&VSC[nf*16+l15][quad<<3]);
      const bf8 v1 = *reinterpret_cast<const bf8*>(&VSC[nf*16+l15][32+(quad<<3)]);
      f32x4 o = MFMA16(pa[0], v0, of[nf]);
      of[nf] = MFMA16(pa[1], v1, o);
    }
    __builtin_amdgcn_s_setprio(0);
    __syncthreads();                                 // single barrier per tile
  };

  for (int kt=0; kt<kend; kt+=128){
    iter(Ks[0], Vs[0], Ks[1], Vs[1], kt);
    if (kt + 64 < kend)
      iter(Ks[1], Vs[1], Ks[0], Vs[0], kt+64);
  }

  // scatter valid rows to ORIGINAL positions (Ob pre-zeroed)
  unsigned short* Op = O + (size_t)bh*SEQ*HDIM;
#pragma unroll
  for (int i=0;i<4;++i){
    const int q = qs + (quad<<2) + i;                // compacted q index
    if (q < kcnt){
      const int orig = Idxb[q];
      const float l = lsv[i];
      const float inv = (l > 0.f) ? 1.f/l : 0.f;
#pragma unroll
      for (int nf=0;nf<4;++nf)
        Op[(size_t)orig*HDIM + (nf<<4) + l15] = f2bf(of[nf][i]*inv);
    }
  }
}

// ---------------------------------------------------------------------------
// MFMA GEMM C v3: chunk-swizzled + LDS-double-buffered gload_lds pipeline
// (same transform as gemm_qkv). LDS 48 KB -> 3 blocks/CU.
// ---------------------------------------------------------------------------
__global__ __launch_bounds__(256) void gemm_out_mfma(
    const unsigned short* __restrict__ A, const unsigned short* __restrict__ Bt,
    float* __restrict__ Out)
{
  __shared__ unsigned short As[2][128][64];
  __shared__ unsigned short Bs[2][64][64];
  const int t = threadIdx.x;
  const int w = t>>6, lane = t&63, quad = lane>>4, l15 = lane&15;
  const int wr = (w>>1)<<6, wc = (w&1)<<5;
  const int linear = blockIdx.y*8 + blockIdx.x;      // grid (8,64) = 512
  const int swz = (linear & 7)*64 + (linear >> 3);   // bijective (512%8==0)
  const int m0 = (swz>>3)<<7, n0 = (swz&7)<<6;
  const int row = t>>3, seg = t&7;
  const int sa = (seg ^ (row & 7)) << 3;             // A source chunk-swizzle
  const int sb = (seg ^ ((row >> 1) & 7)) << 3;      // B source chunk-swizzle
  const unsigned short* Agp = A  + (size_t)(m0+row)*DMODEL + sa;
  const unsigned short* Bgp = Bt + (size_t)(n0+row)*DMODEL + sb;
  f32x4 acc[4][2];
#pragma unroll
  for (int i=0;i<4;++i)
#pragma unroll
    for (int j=0;j<2;++j) acc[i][j] = (f32x4){0.f,0.f,0.f,0.f};

  // prologue: stage k0=0 into buf 0
#pragma unroll
  for (int p=0;p<4;++p)
    gload_lds16(Agp + (size_t)p*32*DMODEL, &As[0][(w<<3)+(p<<5)][0]);
#pragma unroll
  for (int p=0;p<2;++p)
    gload_lds16(Bgp + (size_t)p*32*DMODEL, &Bs[0][(w<<3)+(p<<5)][0]);
  __syncthreads();                                   // buf0 ready

#pragma unroll
  for (int kk=0; kk<DMODEL/64; ++kk){
    const int cur = kk & 1;
    if (kk + 1 < DMODEL/64){                         // loads for k+1 in flight
#pragma unroll
      for (int p=0;p<4;++p)
        gload_lds16(Agp + (size_t)p*32*DMODEL + (kk+1)*64,
                    &As[cur^1][(w<<3)+(p<<5)][0]);
#pragma unroll
      for (int p=0;p<2;++p)
        gload_lds16(Bgp + (size_t)p*32*DMODEL + (kk+1)*64,
                    &Bs[cur^1][(w<<3)+(p<<5)][0]);
    }
#pragma unroll
    for (int ks=0;ks<2;++ks){
      const int co = (((ks<<2)|quad) ^ (l15&7)) << 3;  // swizzled read offset
      bf8 af[4], bfr[2];
#pragma unroll
      for (int mi=0;mi<4;++mi)
        af[mi]  = *reinterpret_cast<const bf8*>(&As[cur][wr+mi*16+l15][co]);
#pragma unroll
      for (int nj=0;nj<2;++nj)
        bfr[nj] = *reinterpret_cast<const bf8*>(&Bs[cur][wc+(l15<<1)+nj][co]);
#pragma unroll
      for (int mi=0;mi<4;++mi)
#pragma unroll
        for (int nj=0;nj<2;++nj) acc[mi][nj] = MFMA16(af[mi], bfr[nj], acc[mi][nj]);
    }
    __syncthreads();                                 // k+1 landed; cur reads done
  }
  const int cbase = n0 + wc + (l15<<1);
#pragma unroll
  for (int mi=0;mi<4;++mi)
#pragma unroll
    for (int i=0;i<4;++i){
      const int m = m0 + wr + mi*16 + quad*4 + i;
      const float2 o = make_float2(acc[mi][0][i], acc[mi][1][i]);
      *reinterpret_cast<float2*>(Out + (size_t)m*DMODEL + cbase) = o;
    }
}

// ---------------------------------------------------------------------------
extern "C" void kernel_launch(void* const* d_in, const int* in_sizes, int n_in,
                              void* d_out, int out_size, void* d_ws, size_t ws_size,
                              hipStream_t stream) {
  (void)in_sizes; (void)n_in; (void)out_size; (void)ws_size;
  const float* x     = (const float*)d_in[0];
  const int*   pmask = (const int*)d_in[2];
  const float* Wqkv  = (const float*)d_in[3];
  const float* Wout  = (const float*)d_in[4];
  float* out = (float*)d_out;

  const size_t per = (size_t)BATCH*NHEADS*SEQ*HDIM;     // 4,194,304
  unsigned short* Xh    = (unsigned short*)d_ws;
  unsigned short* WqkvT = Xh    + (size_t)8192*512;
  unsigned short* WoutT = WqkvT + (size_t)1536*512;
  unsigned short* QKVb  = WoutT + (size_t)512*512;
  unsigned short* VbT   = QKVb  + (size_t)8192*QKV_N;
  unsigned short* Ob    = VbT + per;
  int* Idx = (int*)(Ob + per);                          // [BATCH][SEQ]
  int* Cnt = Idx + (size_t)BATCH*SEQ;                   // [BATCH]

  prep<<<2820, 256, 0, stream>>>(x, Wqkv, Wout, pmask, Xh, WqkvT, WoutT,
                                 Idx, Cnt, Ob);
  gemm_qkv_mfma<<<dim3(QKV_N/128, 8192/128), 256, 0, stream>>>(Xh, WqkvT, QKVb);
  v_transpose<<<dim3(SEQ/64, BATCH*NHEADS), 256, 0, stream>>>(
      QKVb, Idx, Cnt, VbT);
  attn_mfma<<<dim3(SEQ/128, BATCH*NHEADS), 512, 0, stream>>>(
      QKVb, VbT, Idx, Cnt, Ob);
  gemm_out_mfma<<<dim3(DMODEL/64, 8192/128), 256, 0, stream>>>(Ob, WoutT, out);
}